// Round 1
// baseline (554.638 us; speedup 1.0000x reference)
//
#include <hip/hip_runtime.h>

#define NN 50000
#define EE 600000
#define INF 256
#define HF 128

// ---------------- degree counting ----------------
__global__ void count_deg(const int* __restrict__ row, int* __restrict__ cnt, int E) {
    int e = blockIdx.x * blockDim.x + threadIdx.x;
    if (e < E) atomicAdd(&cnt[row[e]], 1);
}

__global__ void finalize_deg(const int* __restrict__ cnt, float* __restrict__ deg_inv,
                             float* __restrict__ dis, int n) {
    int i = blockIdx.x * blockDim.x + threadIdx.x;
    if (i < n) {
        float d = (float)(cnt[i] + 1);
        deg_inv[i] = 1.0f / d;
        dis[i] = rsqrtf(d);
    }
}

// ---------------- 3-phase exclusive scan (for CSR row_start) ----------------
__global__ void scan_phase1(const int* __restrict__ cnt, int* __restrict__ bsum, int n) {
    __shared__ int sdata[256];
    int t = threadIdx.x;
    int i = blockIdx.x * 256 + t;
    sdata[t] = (i < n) ? cnt[i] : 0;
    __syncthreads();
    for (int s = 128; s > 0; s >>= 1) {
        if (t < s) sdata[t] += sdata[t + s];
        __syncthreads();
    }
    if (t == 0) bsum[blockIdx.x] = sdata[0];
}

__global__ void scan_phase2(int* __restrict__ bsum, int nb) {
    __shared__ int sdata[256];
    int t = threadIdx.x;
    int v = (t < nb) ? bsum[t] : 0;
    sdata[t] = v;
    __syncthreads();
    for (int s = 1; s < 256; s <<= 1) {
        int add = (t >= s) ? sdata[t - s] : 0;
        __syncthreads();
        sdata[t] += add;
        __syncthreads();
    }
    if (t < nb) bsum[t] = sdata[t] - v;   // exclusive
}

__global__ void scan_phase3(const int* __restrict__ cnt, const int* __restrict__ bsum,
                            int* __restrict__ row_start, int* __restrict__ fill_pos,
                            int n, int E) {
    __shared__ int sdata[256];
    int t = threadIdx.x;
    int i = blockIdx.x * 256 + t;
    int v = (i < n) ? cnt[i] : 0;
    sdata[t] = v;
    __syncthreads();
    for (int s = 1; s < 256; s <<= 1) {
        int add = (t >= s) ? sdata[t - s] : 0;
        __syncthreads();
        sdata[t] += add;
        __syncthreads();
    }
    if (i < n) {
        int ex = bsum[blockIdx.x] + sdata[t] - v;
        row_start[i] = ex;
        fill_pos[i] = ex;
    }
    if (blockIdx.x == 0 && t == 0) row_start[n] = E;
}

__global__ void fill_csr(const int* __restrict__ row, const int* __restrict__ col,
                         const float* __restrict__ dis, int* __restrict__ fill_pos,
                         int* __restrict__ csr_col, float* __restrict__ csr_wc, int E) {
    int e = blockIdx.x * blockDim.x + threadIdx.x;
    if (e < E) {
        int r = row[e];
        int c = col[e];
        int p = atomicAdd(&fill_pos[r], 1);
        csr_col[p] = c;
        csr_wc[p] = dis[c];
    }
}

// ---------------- f32 GEMM: C[M][128] = A[M][K] @ W[128][K]^T (+bias) ----------------
template <int K>
__global__ __launch_bounds__(256) void gemm_nt128(const float* __restrict__ A,
                                                  const float* __restrict__ W,
                                                  const float* __restrict__ bias,
                                                  float* __restrict__ C, int M) {
    constexpr int TM = 128, TK = 64;
    __shared__ float As[TM][TK];    // 32 KB, k contiguous
    __shared__ float Wt[TK][HF];    // 32 KB, transposed: Wt[k][h]
    const int t = threadIdx.x;
    const int bm = blockIdx.x * TM;
    const int rg = t >> 4;   // 0..15 -> rows rg*8..rg*8+7
    const int cg = t & 15;   // 0..15 -> cols cg*8..cg*8+7

    float acc[8][8];
#pragma unroll
    for (int i = 0; i < 8; ++i)
#pragma unroll
        for (int j = 0; j < 8; ++j) acc[i][j] = 0.f;

    for (int k0 = 0; k0 < K; k0 += TK) {
        // stage A tile: 128x64 = 2048 float4, 8 per thread
#pragma unroll
        for (int r = 0; r < 8; ++r) {
            int f = t + 256 * r;
            int m = f >> 4;
            int kq = f & 15;
            float4 v = make_float4(0.f, 0.f, 0.f, 0.f);
            int gm = bm + m;
            if (gm < M) v = *reinterpret_cast<const float4*>(&A[(size_t)gm * K + k0 + kq * 4]);
            *reinterpret_cast<float4*>(&As[m][kq * 4]) = v;
        }
        // stage W transposed: h = t&127 (conflict-free LDS writes), kq = t>>7 + 2*r
#pragma unroll
        for (int r = 0; r < 8; ++r) {
            int f = t + 256 * r;
            int h = f & 127;
            int kq = f >> 7;
            float4 v = *reinterpret_cast<const float4*>(&W[(size_t)h * K + k0 + kq * 4]);
            Wt[kq * 4 + 0][h] = v.x;
            Wt[kq * 4 + 1][h] = v.y;
            Wt[kq * 4 + 2][h] = v.z;
            Wt[kq * 4 + 3][h] = v.w;
        }
        __syncthreads();

#pragma unroll
        for (int kk = 0; kk < TK; kk += 4) {
            float a[8][4];
#pragma unroll
            for (int i = 0; i < 8; ++i) {
                float4 av = *reinterpret_cast<const float4*>(&As[rg * 8 + i][kk]);
                a[i][0] = av.x; a[i][1] = av.y; a[i][2] = av.z; a[i][3] = av.w;
            }
#pragma unroll
            for (int kq = 0; kq < 4; ++kq) {
                float w[8];
                float4 w0 = *reinterpret_cast<const float4*>(&Wt[kk + kq][cg * 8]);
                float4 w1 = *reinterpret_cast<const float4*>(&Wt[kk + kq][cg * 8 + 4]);
                w[0] = w0.x; w[1] = w0.y; w[2] = w0.z; w[3] = w0.w;
                w[4] = w1.x; w[5] = w1.y; w[6] = w1.z; w[7] = w1.w;
#pragma unroll
                for (int i = 0; i < 8; ++i)
#pragma unroll
                    for (int j = 0; j < 8; ++j)
                        acc[i][j] = fmaf(a[i][kq], w[j], acc[i][j]);
            }
        }
        __syncthreads();
    }

#pragma unroll
    for (int i = 0; i < 8; ++i) {
        int gm = bm + rg * 8 + i;
        if (gm >= M) continue;
#pragma unroll
        for (int jq = 0; jq < 2; ++jq) {
            int h = cg * 8 + jq * 4;
            float4 v;
            v.x = acc[i][jq * 4 + 0];
            v.y = acc[i][jq * 4 + 1];
            v.z = acc[i][jq * 4 + 2];
            v.w = acc[i][jq * 4 + 3];
            if (bias) {
                v.x += bias[h]; v.y += bias[h + 1]; v.z += bias[h + 2]; v.w += bias[h + 3];
            }
            *reinterpret_cast<float4*>(&C[(size_t)gm * HF + h]) = v;
        }
    }
}

// ---------------- combine: out = conv_b + relu(h+root)*deg_inv + deg_inv*xw ----------------
__global__ void combine_init(const float* __restrict__ h, const float* __restrict__ xw,
                             const float* __restrict__ conv_b, const float* __restrict__ root,
                             const float* __restrict__ deg_inv, float* __restrict__ out, int n) {
    int idx = blockIdx.x * blockDim.x + threadIdx.x;  // n*32 float4 slots
    if (idx >= n * 32) return;
    int node = idx >> 5;
    int q = idx & 31;
    float di = deg_inv[node];
    float4 hv = *reinterpret_cast<const float4*>(&h[(size_t)node * HF + q * 4]);
    float4 xv = *reinterpret_cast<const float4*>(&xw[(size_t)node * HF + q * 4]);
    float4 rv = *reinterpret_cast<const float4*>(&root[q * 4]);
    float4 cb = *reinterpret_cast<const float4*>(&conv_b[q * 4]);
    float4 o;
    o.x = cb.x + fmaxf(hv.x + rv.x, 0.f) * di + di * xv.x;
    o.y = cb.y + fmaxf(hv.y + rv.y, 0.f) * di + di * xv.y;
    o.z = cb.z + fmaxf(hv.z + rv.z, 0.f) * di + di * xv.z;
    o.w = cb.w + fmaxf(hv.w + rv.w, 0.f) * di + di * xv.w;
    *reinterpret_cast<float4*>(&out[(size_t)node * HF + q * 4]) = o;
}

// ---------------- CSR message accumulation: one wave per target node ----------------
__global__ void message_csr(const int* __restrict__ row_start, const int* __restrict__ csr_col,
                            const float* __restrict__ csr_wc, const float* __restrict__ dis,
                            const float* __restrict__ xw, float* __restrict__ out, int n) {
    int wid = (blockIdx.x * blockDim.x + threadIdx.x) >> 6;
    int lane = threadIdx.x & 63;
    if (wid >= n) return;
    int s = row_start[wid];
    int e = row_start[wid + 1];
    float dn = dis[wid];
    float ax = 0.f, ay = 0.f;
    for (int j = s; j < e; ++j) {
        int c = csr_col[j];
        float wc = csr_wc[j];
        float2 xv = *reinterpret_cast<const float2*>(&xw[(size_t)c * HF + lane * 2]);
        ax = fmaf(wc, xv.x, ax);
        ay = fmaf(wc, xv.y, ay);
    }
    float2* o = reinterpret_cast<float2*>(&out[(size_t)wid * HF + lane * 2]);
    float2 cur = *o;
    cur.x += dn * ax;
    cur.y += dn * ay;
    *o = cur;
}

// ---------------- residual + layernorm + relu (wave per node, in-place into h0) --------
__global__ void resid_ln_relu(float* __restrict__ h0, const float* __restrict__ h1,
                              const float* __restrict__ gamma, const float* __restrict__ beta,
                              int n) {
    int wid = (blockIdx.x * blockDim.x + threadIdx.x) >> 6;
    int lane = threadIdx.x & 63;
    if (wid >= n) return;
    float2 x = *reinterpret_cast<const float2*>(&h1[(size_t)wid * HF + lane * 2]);
    float2 o = *reinterpret_cast<const float2*>(&h0[(size_t)wid * HF + lane * 2]);
    x.x += o.x;
    x.y += o.y;
    float s = x.x + x.y;
#pragma unroll
    for (int m = 1; m < 64; m <<= 1) s += __shfl_xor(s, m, 64);
    float mu = s * (1.0f / HF);
    float dx = x.x - mu, dy = x.y - mu;
    float v = dx * dx + dy * dy;
#pragma unroll
    for (int m = 1; m < 64; m <<= 1) v += __shfl_xor(v, m, 64);
    float r = rsqrtf(v * (1.0f / HF) + 1e-5f);
    float2 g = *reinterpret_cast<const float2*>(&gamma[lane * 2]);
    float2 b = *reinterpret_cast<const float2*>(&beta[lane * 2]);
    float2 t;
    t.x = fmaxf(dx * r * g.x + b.x, 0.f);
    t.y = fmaxf(dy * r * g.y + b.y, 0.f);
    *reinterpret_cast<float2*>(&h0[(size_t)wid * HF + lane * 2]) = t;
}

extern "C" void kernel_launch(void* const* d_in, const int* in_sizes, int n_in,
                              void* d_out, int out_size, void* d_ws, size_t ws_size,
                              hipStream_t stream) {
    const int N = NN, E = EE;
    const float* in_feat = (const float*)d_in[0];
    const int* row = (const int*)d_in[1];
    const int* col = (const int*)d_in[2];
    const float* lin_w = (const float*)d_in[3];
    const float* lin_b = (const float*)d_in[4];
    const float* conv_w = (const float*)d_in[5];
    const float* conv_b = (const float*)d_in[6];
    const float* root_emb = (const float*)d_in[7];
    const float* ln_gamma = (const float*)d_in[8];
    const float* ln_beta = (const float*)d_in[9];
    float* out = (float*)d_out;

    // workspace layout (4B units)
    float* ws = (float*)d_ws;
    float* deg_inv = ws;                       // N
    float* dis = deg_inv + N;                  // N
    int* cnt = (int*)(dis + N);                // N
    int* row_start = cnt + N;                  // N+1
    int* fill_pos = row_start + N + 1;         // N
    int* bsum = fill_pos + N;                  // 256
    int* csr_col = bsum + 256;                 // E
    float* csr_wc = (float*)(csr_col + E);     // E
    size_t off = (size_t)(csr_wc + E - ws);
    off = (off + 3) & ~(size_t)3;              // 16B align
    float* h0 = ws + off;                      // N*HF
    float* xw = h0 + (size_t)N * HF;           // N*HF

    const int NB = (N + 255) / 256;

    hipMemsetAsync(cnt, 0, N * sizeof(int), stream);
    count_deg<<<(E + 255) / 256, 256, 0, stream>>>(row, cnt, E);
    finalize_deg<<<NB, 256, 0, stream>>>(cnt, deg_inv, dis, N);
    scan_phase1<<<NB, 256, 0, stream>>>(cnt, bsum, N);
    scan_phase2<<<1, 256, 0, stream>>>(bsum, NB);
    scan_phase3<<<NB, 256, 0, stream>>>(cnt, bsum, row_start, fill_pos, N, E);
    fill_csr<<<(E + 255) / 256, 256, 0, stream>>>(row, col, dis, fill_pos, csr_col, csr_wc, E);

    // h0 = in_feat @ lin_w.T + lin_b
    gemm_nt128<INF><<<(N + 127) / 128, 256, 0, stream>>>(in_feat, lin_w, lin_b, h0, N);

    // ---- prop step 0 ----
    gemm_nt128<HF><<<(N + 127) / 128, 256, 0, stream>>>(h0, conv_w, nullptr, xw, N);
    combine_init<<<(N * 32 + 255) / 256, 256, 0, stream>>>(h0, xw, conv_b, root_emb, deg_inv, out, N);
    message_csr<<<(N + 3) / 4, 256, 0, stream>>>(row_start, csr_col, csr_wc, dis, xw, out, N);

    // ---- prop step 1 ----
    // h0 <- relu(LN(out + h0; gamma[1], beta[1]))
    resid_ln_relu<<<(N + 3) / 4, 256, 0, stream>>>(h0, out, ln_gamma + HF, ln_beta + HF, N);
    gemm_nt128<HF><<<(N + 127) / 128, 256, 0, stream>>>(h0, conv_w, nullptr, xw, N);
    combine_init<<<(N * 32 + 255) / 256, 256, 0, stream>>>(h0, xw, conv_b, root_emb, deg_inv, out, N);
    message_csr<<<(N + 3) / 4, 256, 0, stream>>>(row_start, csr_col, csr_wc, dis, xw, out, N);
}

// Round 2
// 422.526 us; speedup vs baseline: 1.3127x; 1.3127x over previous
//
#include <hip/hip_runtime.h>

#define NN 50000
#define EE 600000
#define INF 256
#define HF 128

typedef __attribute__((ext_vector_type(8))) short short8;
typedef __attribute__((ext_vector_type(4))) float floatx4;

// ---------------- bf16 helpers ----------------
__device__ __forceinline__ unsigned short f32_to_bf16_rne(float x) {
    unsigned int u = __float_as_uint(x);
    unsigned int r = (u + 0x7FFFu + ((u >> 16) & 1u)) >> 16;
    return (unsigned short)r;
}
__device__ __forceinline__ float bf16_to_f32(unsigned short h) {
    return __uint_as_float(((unsigned int)h) << 16);
}

// ---------------- degree counting ----------------
__global__ void count_deg(const int* __restrict__ row, int* __restrict__ cnt, int E) {
    int e = blockIdx.x * blockDim.x + threadIdx.x;
    if (e < E) atomicAdd(&cnt[row[e]], 1);
}

__global__ void finalize_deg(const int* __restrict__ cnt, float* __restrict__ deg_inv,
                             float* __restrict__ dis, int n) {
    int i = blockIdx.x * blockDim.x + threadIdx.x;
    if (i < n) {
        float d = (float)(cnt[i] + 1);
        deg_inv[i] = 1.0f / d;
        dis[i] = rsqrtf(d);
    }
}

// ---------------- 3-phase exclusive scan (for CSR row_start) ----------------
__global__ void scan_phase1(const int* __restrict__ cnt, int* __restrict__ bsum, int n) {
    __shared__ int sdata[256];
    int t = threadIdx.x;
    int i = blockIdx.x * 256 + t;
    sdata[t] = (i < n) ? cnt[i] : 0;
    __syncthreads();
    for (int s = 128; s > 0; s >>= 1) {
        if (t < s) sdata[t] += sdata[t + s];
        __syncthreads();
    }
    if (t == 0) bsum[blockIdx.x] = sdata[0];
}

__global__ void scan_phase2(int* __restrict__ bsum, int nb) {
    __shared__ int sdata[256];
    int t = threadIdx.x;
    int v = (t < nb) ? bsum[t] : 0;
    sdata[t] = v;
    __syncthreads();
    for (int s = 1; s < 256; s <<= 1) {
        int add = (t >= s) ? sdata[t - s] : 0;
        __syncthreads();
        sdata[t] += add;
        __syncthreads();
    }
    if (t < nb) bsum[t] = sdata[t] - v;   // exclusive
}

__global__ void scan_phase3(const int* __restrict__ cnt, const int* __restrict__ bsum,
                            int* __restrict__ row_start, int* __restrict__ fill_pos,
                            int n, int E) {
    __shared__ int sdata[256];
    int t = threadIdx.x;
    int i = blockIdx.x * 256 + t;
    int v = (i < n) ? cnt[i] : 0;
    sdata[t] = v;
    __syncthreads();
    for (int s = 1; s < 256; s <<= 1) {
        int add = (t >= s) ? sdata[t - s] : 0;
        __syncthreads();
        sdata[t] += add;
        __syncthreads();
    }
    if (i < n) {
        int ex = bsum[blockIdx.x] + sdata[t] - v;
        row_start[i] = ex;
        fill_pos[i] = ex;
    }
    if (blockIdx.x == 0 && t == 0) row_start[n] = E;
}

__global__ void fill_csr(const int* __restrict__ row, const int* __restrict__ col,
                         const float* __restrict__ dis, int* __restrict__ fill_pos,
                         int* __restrict__ csr_col, float* __restrict__ csr_wc, int E) {
    int e = blockIdx.x * blockDim.x + threadIdx.x;
    if (e < E) {
        int r = row[e];
        int c = col[e];
        int p = atomicAdd(&fill_pos[r], 1);
        csr_col[p] = c;
        csr_wc[p] = dis[c];
    }
}

// ---------------- split-bf16 MFMA GEMM: C[M][128] = A[M][K] @ W[128][K]^T (+bias) -------
// f32 emulation: a = a_hi + a_lo (bf16), w = w_hi + w_lo; D = ah*wh + al*wh + ah*wl.
// Dropped al*wl term is O(2^-18 * |a w|) -> negligible vs 4.6e-2 budget.
// Fragment layouts (HW-verified m89/m91/m120): A/B lane m(n)=lane&15, k=(lane>>4)*8+j;
// C/D col=lane&15, row=(lane>>4)*4+reg.
template <int K>
__global__ __launch_bounds__(256) void gemm_mfma(const float* __restrict__ A,
                                                 const float* __restrict__ W,
                                                 const float* __restrict__ bias,
                                                 float* __restrict__ C, int M) {
    constexpr int TK = 32;
    constexpr int LDA = 40;  // bf16 row stride: 80 B = 20 banks -> <=2-way conflicts (free)
    __shared__ unsigned short Ah[128 * LDA];
    __shared__ unsigned short Al[128 * LDA];
    __shared__ unsigned short Wh[128 * LDA];
    __shared__ unsigned short Wl[128 * LDA];   // 4 x 10 KB = 40 KB

    const int t = threadIdx.x;
    const int bm = blockIdx.x * 128;
    const int wave = t >> 6;
    const int lane = t & 63;
    const int lrow = lane & 15;
    const int kbase = (lane >> 4) * 8;

    floatx4 acc[2][8];
#pragma unroll
    for (int mt = 0; mt < 2; ++mt)
#pragma unroll
        for (int nt = 0; nt < 8; ++nt) acc[mt][nt] = (floatx4){0.f, 0.f, 0.f, 0.f};

    for (int k0 = 0; k0 < K; k0 += TK) {
        // stage A tile 128x32 f32 -> hi/lo bf16 (1024 float4 loads, 4/thread)
#pragma unroll
        for (int r = 0; r < 4; ++r) {
            int f = t + 256 * r;
            int rw = f >> 3;
            int cq = f & 7;
            float4 v = make_float4(0.f, 0.f, 0.f, 0.f);
            int gr = bm + rw;
            if (gr < M) v = *reinterpret_cast<const float4*>(&A[(size_t)gr * K + k0 + cq * 4]);
            unsigned short hx = f32_to_bf16_rne(v.x), hy = f32_to_bf16_rne(v.y),
                           hz = f32_to_bf16_rne(v.z), hw = f32_to_bf16_rne(v.w);
            unsigned short lx = f32_to_bf16_rne(v.x - bf16_to_f32(hx)),
                           ly = f32_to_bf16_rne(v.y - bf16_to_f32(hy)),
                           lz = f32_to_bf16_rne(v.z - bf16_to_f32(hz)),
                           lw = f32_to_bf16_rne(v.w - bf16_to_f32(hw));
            uint2 hp, lp;
            hp.x = (unsigned)hx | ((unsigned)hy << 16);
            hp.y = (unsigned)hz | ((unsigned)hw << 16);
            lp.x = (unsigned)lx | ((unsigned)ly << 16);
            lp.y = (unsigned)lz | ((unsigned)lw << 16);
            *reinterpret_cast<uint2*>(&Ah[rw * LDA + cq * 4]) = hp;
            *reinterpret_cast<uint2*>(&Al[rw * LDA + cq * 4]) = lp;
        }
        // stage W tile 128x32 (always in-bounds: W is 128 x K)
#pragma unroll
        for (int r = 0; r < 4; ++r) {
            int f = t + 256 * r;
            int rw = f >> 3;
            int cq = f & 7;
            float4 v = *reinterpret_cast<const float4*>(&W[(size_t)rw * K + k0 + cq * 4]);
            unsigned short hx = f32_to_bf16_rne(v.x), hy = f32_to_bf16_rne(v.y),
                           hz = f32_to_bf16_rne(v.z), hw = f32_to_bf16_rne(v.w);
            unsigned short lx = f32_to_bf16_rne(v.x - bf16_to_f32(hx)),
                           ly = f32_to_bf16_rne(v.y - bf16_to_f32(hy)),
                           lz = f32_to_bf16_rne(v.z - bf16_to_f32(hz)),
                           lw = f32_to_bf16_rne(v.w - bf16_to_f32(hw));
            uint2 hp, lp;
            hp.x = (unsigned)hx | ((unsigned)hy << 16);
            hp.y = (unsigned)hz | ((unsigned)hw << 16);
            lp.x = (unsigned)lx | ((unsigned)ly << 16);
            lp.y = (unsigned)lz | ((unsigned)lw << 16);
            *reinterpret_cast<uint2*>(&Wh[rw * LDA + cq * 4]) = hp;
            *reinterpret_cast<uint2*>(&Wl[rw * LDA + cq * 4]) = lp;
        }
        __syncthreads();

        short8 afh[2], afl[2], bfh[8], bfl[8];
#pragma unroll
        for (int mt = 0; mt < 2; ++mt) {
            int rw = wave * 32 + mt * 16 + lrow;
            afh[mt] = *reinterpret_cast<const short8*>(&Ah[rw * LDA + kbase]);
            afl[mt] = *reinterpret_cast<const short8*>(&Al[rw * LDA + kbase]);
        }
#pragma unroll
        for (int nt = 0; nt < 8; ++nt) {
            int rw = nt * 16 + lrow;
            bfh[nt] = *reinterpret_cast<const short8*>(&Wh[rw * LDA + kbase]);
            bfl[nt] = *reinterpret_cast<const short8*>(&Wl[rw * LDA + kbase]);
        }
#pragma unroll
        for (int mt = 0; mt < 2; ++mt)
#pragma unroll
            for (int nt = 0; nt < 8; ++nt) {
                acc[mt][nt] = __builtin_amdgcn_mfma_f32_16x16x32_bf16(afh[mt], bfh[nt], acc[mt][nt], 0, 0, 0);
                acc[mt][nt] = __builtin_amdgcn_mfma_f32_16x16x32_bf16(afl[mt], bfh[nt], acc[mt][nt], 0, 0, 0);
                acc[mt][nt] = __builtin_amdgcn_mfma_f32_16x16x32_bf16(afh[mt], bfl[nt], acc[mt][nt], 0, 0, 0);
            }
        __syncthreads();
    }

    // epilogue: C/D layout col=lane&15, row=(lane>>4)*4+reg
#pragma unroll
    for (int mt = 0; mt < 2; ++mt) {
#pragma unroll
        for (int r = 0; r < 4; ++r) {
            int grow = bm + wave * 32 + mt * 16 + (lane >> 4) * 4 + r;
            if (grow < M) {
#pragma unroll
                for (int nt = 0; nt < 8; ++nt) {
                    int colh = nt * 16 + (lane & 15);
                    float v = acc[mt][nt][r];
                    if (bias) v += bias[colh];
                    C[(size_t)grow * HF + colh] = v;
                }
            }
        }
    }
}

// ---------------- fused CSR message + combine: one wave per target node ----------------
// out = conv_b + relu(h+root)*deg_inv + deg_inv*xw_self + dis[wid]*sum_e dis[c]*xw[c]
__global__ void message_fused(const int* __restrict__ row_start, const int* __restrict__ csr_col,
                              const float* __restrict__ csr_wc, const float* __restrict__ dis,
                              const float* __restrict__ deg_inv, const float* __restrict__ h,
                              const float* __restrict__ xw, const float* __restrict__ conv_b,
                              const float* __restrict__ root, float* __restrict__ out, int n) {
    int wid = (blockIdx.x * blockDim.x + threadIdx.x) >> 6;
    int lane = threadIdx.x & 63;
    if (wid >= n) return;
    int s = row_start[wid];
    int e = row_start[wid + 1];
    float dn = dis[wid];
    float di = deg_inv[wid];
    float ax = 0.f, ay = 0.f;
    for (int j = s; j < e; ++j) {
        int c = csr_col[j];
        float wc = csr_wc[j];
        float2 xv = *reinterpret_cast<const float2*>(&xw[(size_t)c * HF + lane * 2]);
        ax = fmaf(wc, xv.x, ax);
        ay = fmaf(wc, xv.y, ay);
    }
    float2 hv = *reinterpret_cast<const float2*>(&h[(size_t)wid * HF + lane * 2]);
    float2 sv = *reinterpret_cast<const float2*>(&xw[(size_t)wid * HF + lane * 2]);
    float2 rv = *reinterpret_cast<const float2*>(&root[lane * 2]);
    float2 cb = *reinterpret_cast<const float2*>(&conv_b[lane * 2]);
    float2 o;
    o.x = cb.x + fmaxf(hv.x + rv.x, 0.f) * di + di * sv.x + dn * ax;
    o.y = cb.y + fmaxf(hv.y + rv.y, 0.f) * di + di * sv.y + dn * ay;
    *reinterpret_cast<float2*>(&out[(size_t)wid * HF + lane * 2]) = o;
}

// ---------------- residual + layernorm + relu (wave per node, in-place into h0) --------
__global__ void resid_ln_relu(float* __restrict__ h0, const float* __restrict__ h1,
                              const float* __restrict__ gamma, const float* __restrict__ beta,
                              int n) {
    int wid = (blockIdx.x * blockDim.x + threadIdx.x) >> 6;
    int lane = threadIdx.x & 63;
    if (wid >= n) return;
    float2 x = *reinterpret_cast<const float2*>(&h1[(size_t)wid * HF + lane * 2]);
    float2 o = *reinterpret_cast<const float2*>(&h0[(size_t)wid * HF + lane * 2]);
    x.x += o.x;
    x.y += o.y;
    float s = x.x + x.y;
#pragma unroll
    for (int m = 1; m < 64; m <<= 1) s += __shfl_xor(s, m, 64);
    float mu = s * (1.0f / HF);
    float dx = x.x - mu, dy = x.y - mu;
    float v = dx * dx + dy * dy;
#pragma unroll
    for (int m = 1; m < 64; m <<= 1) v += __shfl_xor(v, m, 64);
    float r = rsqrtf(v * (1.0f / HF) + 1e-5f);
    float2 g = *reinterpret_cast<const float2*>(&gamma[lane * 2]);
    float2 b = *reinterpret_cast<const float2*>(&beta[lane * 2]);
    float2 t;
    t.x = fmaxf(dx * r * g.x + b.x, 0.f);
    t.y = fmaxf(dy * r * g.y + b.y, 0.f);
    *reinterpret_cast<float2*>(&h0[(size_t)wid * HF + lane * 2]) = t;
}

extern "C" void kernel_launch(void* const* d_in, const int* in_sizes, int n_in,
                              void* d_out, int out_size, void* d_ws, size_t ws_size,
                              hipStream_t stream) {
    const int N = NN, E = EE;
    const float* in_feat = (const float*)d_in[0];
    const int* row = (const int*)d_in[1];
    const int* col = (const int*)d_in[2];
    const float* lin_w = (const float*)d_in[3];
    const float* lin_b = (const float*)d_in[4];
    const float* conv_w = (const float*)d_in[5];
    const float* conv_b = (const float*)d_in[6];
    const float* root_emb = (const float*)d_in[7];
    const float* ln_gamma = (const float*)d_in[8];
    const float* ln_beta = (const float*)d_in[9];
    float* out = (float*)d_out;

    // workspace layout (4B units)
    float* ws = (float*)d_ws;
    float* deg_inv = ws;                       // N
    float* dis = deg_inv + N;                  // N
    int* cnt = (int*)(dis + N);                // N
    int* row_start = cnt + N;                  // N+1
    int* fill_pos = row_start + N + 1;         // N
    int* bsum = fill_pos + N;                  // 256
    int* csr_col = bsum + 256;                 // E
    float* csr_wc = (float*)(csr_col + E);     // E
    size_t off = (size_t)(csr_wc + E - ws);
    off = (off + 3) & ~(size_t)3;              // 16B align
    float* h0 = ws + off;                      // N*HF
    float* xw = h0 + (size_t)N * HF;           // N*HF

    const int NB = (N + 255) / 256;

    hipMemsetAsync(cnt, 0, N * sizeof(int), stream);
    count_deg<<<(E + 255) / 256, 256, 0, stream>>>(row, cnt, E);
    finalize_deg<<<NB, 256, 0, stream>>>(cnt, deg_inv, dis, N);
    scan_phase1<<<NB, 256, 0, stream>>>(cnt, bsum, N);
    scan_phase2<<<1, 256, 0, stream>>>(bsum, NB);
    scan_phase3<<<NB, 256, 0, stream>>>(cnt, bsum, row_start, fill_pos, N, E);
    fill_csr<<<(E + 255) / 256, 256, 0, stream>>>(row, col, dis, fill_pos, csr_col, csr_wc, E);

    const int GB = (N + 127) / 128;

    // h0 = in_feat @ lin_w.T + lin_b
    gemm_mfma<INF><<<GB, 256, 0, stream>>>(in_feat, lin_w, lin_b, h0, N);

    // ---- prop step 0 ----
    gemm_mfma<HF><<<GB, 256, 0, stream>>>(h0, conv_w, nullptr, xw, N);
    message_fused<<<(N + 3) / 4, 256, 0, stream>>>(row_start, csr_col, csr_wc, dis, deg_inv,
                                                   h0, xw, conv_b, root_emb, out, N);

    // ---- prop step 1 ----
    resid_ln_relu<<<(N + 3) / 4, 256, 0, stream>>>(h0, out, ln_gamma + HF, ln_beta + HF, N);
    gemm_mfma<HF><<<GB, 256, 0, stream>>>(h0, conv_w, nullptr, xw, N);
    message_fused<<<(N + 3) / 4, 256, 0, stream>>>(row_start, csr_col, csr_wc, dis, deg_inv,
                                                   h0, xw, conv_b, root_emb, out, N);
}

// Round 3
// 355.747 us; speedup vs baseline: 1.5591x; 1.1877x over previous
//
#include <hip/hip_runtime.h>

#define NN 50000
#define EE 600000
#define INF 256
#define HF 128

typedef __attribute__((ext_vector_type(8))) short short8;
typedef __attribute__((ext_vector_type(4))) float floatx4;

// ---------------- bf16 helpers ----------------
__device__ __forceinline__ unsigned short f32_to_bf16_rne(float x) {
    unsigned int u = __float_as_uint(x);
    unsigned int r = (u + 0x7FFFu + ((u >> 16) & 1u)) >> 16;
    return (unsigned short)r;
}
__device__ __forceinline__ float bf16_to_f32(unsigned short h) {
    return __uint_as_float(((unsigned int)h) << 16);
}

// ---------------- degree counting ----------------
__global__ void count_deg(const int* __restrict__ row, int* __restrict__ cnt, int E) {
    int e = blockIdx.x * blockDim.x + threadIdx.x;
    if (e < E) atomicAdd(&cnt[row[e]], 1);
}

// ---------------- 3-phase exclusive scan (for CSR row_start) ----------------
__global__ void scan_phase1(const int* __restrict__ cnt, int* __restrict__ bsum, int n) {
    __shared__ int sdata[256];
    int t = threadIdx.x;
    int i = blockIdx.x * 256 + t;
    sdata[t] = (i < n) ? cnt[i] : 0;
    __syncthreads();
    for (int s = 128; s > 0; s >>= 1) {
        if (t < s) sdata[t] += sdata[t + s];
        __syncthreads();
    }
    if (t == 0) bsum[blockIdx.x] = sdata[0];
}

__global__ void scan_phase2(int* __restrict__ bsum, int nb) {
    __shared__ int sdata[256];
    int t = threadIdx.x;
    int v = (t < nb) ? bsum[t] : 0;
    sdata[t] = v;
    __syncthreads();
    for (int s = 1; s < 256; s <<= 1) {
        int add = (t >= s) ? sdata[t - s] : 0;
        __syncthreads();
        sdata[t] += add;
        __syncthreads();
    }
    if (t < nb) bsum[t] = sdata[t] - v;   // exclusive
}

// scan_phase3 + finalize_deg folded
__global__ void scan_phase3(const int* __restrict__ cnt, const int* __restrict__ bsum,
                            int* __restrict__ row_start, int* __restrict__ fill_pos,
                            float* __restrict__ deg_inv, float* __restrict__ dis,
                            int n, int E) {
    __shared__ int sdata[256];
    int t = threadIdx.x;
    int i = blockIdx.x * 256 + t;
    int v = (i < n) ? cnt[i] : 0;
    sdata[t] = v;
    __syncthreads();
    for (int s = 1; s < 256; s <<= 1) {
        int add = (t >= s) ? sdata[t - s] : 0;
        __syncthreads();
        sdata[t] += add;
        __syncthreads();
    }
    if (i < n) {
        int ex = bsum[blockIdx.x] + sdata[t] - v;
        row_start[i] = ex;
        fill_pos[i] = ex;
        float d = (float)(v + 1);
        deg_inv[i] = 1.0f / d;
        dis[i] = rsqrtf(d);
    }
    if (blockIdx.x == 0 && t == 0) row_start[n] = E;
}

__global__ void fill_csr(const int* __restrict__ row, const int* __restrict__ col,
                         const float* __restrict__ dis, int* __restrict__ fill_pos,
                         int* __restrict__ csr_col, float* __restrict__ csr_wc, int E) {
    int e = blockIdx.x * blockDim.x + threadIdx.x;
    if (e < E) {
        int r = row[e];
        int c = col[e];
        int p = atomicAdd(&fill_pos[r], 1);
        csr_col[p] = c;
        csr_wc[p] = dis[c];
    }
}

// ---------------- split-bf16 MFMA GEMM: C[M][128] = A[M][K] @ W[128][K]^T -------
// FUSE=false: C = acc + bias; also writes bf16 copy of C to Cbf.
// FUSE=true : C = acc + conv_b[col] + relu(h[row][col]+root[col])*deg_inv[row]  (combine fused)
template <int K, bool FUSE>
__global__ __launch_bounds__(256) void gemm_mfma(const float* __restrict__ A,
                                                 const float* __restrict__ W,
                                                 const float* __restrict__ bias,
                                                 float* __restrict__ C,
                                                 unsigned short* __restrict__ Cbf,
                                                 const float* __restrict__ h,
                                                 const float* __restrict__ deg_inv,
                                                 const float* __restrict__ root,
                                                 int M) {
    constexpr int TK = 32;
    constexpr int LDA = 40;  // bf16 row stride: 80 B = 20 banks -> <=2-way conflicts (free)
    __shared__ unsigned short Ah[128 * LDA];
    __shared__ unsigned short Al[128 * LDA];
    __shared__ unsigned short Wh[128 * LDA];
    __shared__ unsigned short Wl[128 * LDA];

    const int t = threadIdx.x;
    const int bm = blockIdx.x * 128;
    const int wave = t >> 6;
    const int lane = t & 63;
    const int lrow = lane & 15;
    const int kbase = (lane >> 4) * 8;

    floatx4 acc[2][8];
#pragma unroll
    for (int mt = 0; mt < 2; ++mt)
#pragma unroll
        for (int nt = 0; nt < 8; ++nt) acc[mt][nt] = (floatx4){0.f, 0.f, 0.f, 0.f};

    for (int k0 = 0; k0 < K; k0 += TK) {
#pragma unroll
        for (int r = 0; r < 4; ++r) {
            int f = t + 256 * r;
            int rw = f >> 3;
            int cq = f & 7;
            float4 v = make_float4(0.f, 0.f, 0.f, 0.f);
            int gr = bm + rw;
            if (gr < M) v = *reinterpret_cast<const float4*>(&A[(size_t)gr * K + k0 + cq * 4]);
            unsigned short hx = f32_to_bf16_rne(v.x), hy = f32_to_bf16_rne(v.y),
                           hz = f32_to_bf16_rne(v.z), hw = f32_to_bf16_rne(v.w);
            unsigned short lx = f32_to_bf16_rne(v.x - bf16_to_f32(hx)),
                           ly = f32_to_bf16_rne(v.y - bf16_to_f32(hy)),
                           lz = f32_to_bf16_rne(v.z - bf16_to_f32(hz)),
                           lw = f32_to_bf16_rne(v.w - bf16_to_f32(hw));
            uint2 hp, lp;
            hp.x = (unsigned)hx | ((unsigned)hy << 16);
            hp.y = (unsigned)hz | ((unsigned)hw << 16);
            lp.x = (unsigned)lx | ((unsigned)ly << 16);
            lp.y = (unsigned)lz | ((unsigned)lw << 16);
            *reinterpret_cast<uint2*>(&Ah[rw * LDA + cq * 4]) = hp;
            *reinterpret_cast<uint2*>(&Al[rw * LDA + cq * 4]) = lp;
        }
#pragma unroll
        for (int r = 0; r < 4; ++r) {
            int f = t + 256 * r;
            int rw = f >> 3;
            int cq = f & 7;
            float4 v = *reinterpret_cast<const float4*>(&W[(size_t)rw * K + k0 + cq * 4]);
            unsigned short hx = f32_to_bf16_rne(v.x), hy = f32_to_bf16_rne(v.y),
                           hz = f32_to_bf16_rne(v.z), hw = f32_to_bf16_rne(v.w);
            unsigned short lx = f32_to_bf16_rne(v.x - bf16_to_f32(hx)),
                           ly = f32_to_bf16_rne(v.y - bf16_to_f32(hy)),
                           lz = f32_to_bf16_rne(v.z - bf16_to_f32(hz)),
                           lw = f32_to_bf16_rne(v.w - bf16_to_f32(hw));
            uint2 hp, lp;
            hp.x = (unsigned)hx | ((unsigned)hy << 16);
            hp.y = (unsigned)hz | ((unsigned)hw << 16);
            lp.x = (unsigned)lx | ((unsigned)ly << 16);
            lp.y = (unsigned)lz | ((unsigned)lw << 16);
            *reinterpret_cast<uint2*>(&Wh[rw * LDA + cq * 4]) = hp;
            *reinterpret_cast<uint2*>(&Wl[rw * LDA + cq * 4]) = lp;
        }
        __syncthreads();

        short8 afh[2], afl[2], bfh[8], bfl[8];
#pragma unroll
        for (int mt = 0; mt < 2; ++mt) {
            int rw = wave * 32 + mt * 16 + lrow;
            afh[mt] = *reinterpret_cast<const short8*>(&Ah[rw * LDA + kbase]);
            afl[mt] = *reinterpret_cast<const short8*>(&Al[rw * LDA + kbase]);
        }
#pragma unroll
        for (int nt = 0; nt < 8; ++nt) {
            int rw = nt * 16 + lrow;
            bfh[nt] = *reinterpret_cast<const short8*>(&Wh[rw * LDA + kbase]);
            bfl[nt] = *reinterpret_cast<const short8*>(&Wl[rw * LDA + kbase]);
        }
#pragma unroll
        for (int mt = 0; mt < 2; ++mt)
#pragma unroll
            for (int nt = 0; nt < 8; ++nt) {
                acc[mt][nt] = __builtin_amdgcn_mfma_f32_16x16x32_bf16(afh[mt], bfh[nt], acc[mt][nt], 0, 0, 0);
                acc[mt][nt] = __builtin_amdgcn_mfma_f32_16x16x32_bf16(afl[mt], bfh[nt], acc[mt][nt], 0, 0, 0);
                acc[mt][nt] = __builtin_amdgcn_mfma_f32_16x16x32_bf16(afh[mt], bfl[nt], acc[mt][nt], 0, 0, 0);
            }
        __syncthreads();
    }

    // epilogue: C/D layout col=lane&15, row=(lane>>4)*4+reg
#pragma unroll
    for (int mt = 0; mt < 2; ++mt) {
#pragma unroll
        for (int r = 0; r < 4; ++r) {
            int grow = bm + wave * 32 + mt * 16 + (lane >> 4) * 4 + r;
            if (grow < M) {
                float di = FUSE ? deg_inv[grow] : 0.f;
#pragma unroll
                for (int nt = 0; nt < 8; ++nt) {
                    int colh = nt * 16 + (lane & 15);
                    float v = acc[mt][nt][r];
                    if (FUSE) {
                        v += bias[colh];  // conv_b
                        float hv = h[(size_t)grow * HF + colh];
                        v += fmaxf(hv + root[colh], 0.f) * di;
                        C[(size_t)grow * HF + colh] = v;
                    } else {
                        if (bias) v += bias[colh];
                        C[(size_t)grow * HF + colh] = v;
                        Cbf[(size_t)grow * HF + colh] = f32_to_bf16_rne(v);
                    }
                }
            }
        }
    }
}

// ---------------- aggregate: agg[t] = dis[t]*sum_e dis[c]*hbf[c] + deg_inv[t]*h[t] ------
// one wave per node; half-wave per edge (2 gathers in flight); bf16 gather rows (256 B)
__global__ void aggregate(const int* __restrict__ row_start, const int* __restrict__ csr_col,
                          const float* __restrict__ csr_wc, const float* __restrict__ dis,
                          const float* __restrict__ deg_inv, const float* __restrict__ h,
                          const unsigned short* __restrict__ hbf, float* __restrict__ agg,
                          int n) {
    int wid = (blockIdx.x * blockDim.x + threadIdx.x) >> 6;
    int lane = threadIdx.x & 63;
    if (wid >= n) return;
    int half = lane >> 5;
    int l32 = lane & 31;
    int s = row_start[wid];
    int e = row_start[wid + 1];
    float a0 = 0.f, a1 = 0.f, a2 = 0.f, a3 = 0.f;
#pragma unroll 2
    for (int j = s + half; j < e; j += 2) {
        int c = csr_col[j];
        float wc = csr_wc[j];
        ushort4 hv = *reinterpret_cast<const ushort4*>(&hbf[(size_t)c * HF + l32 * 4]);
        a0 = fmaf(wc, bf16_to_f32(hv.x), a0);
        a1 = fmaf(wc, bf16_to_f32(hv.y), a1);
        a2 = fmaf(wc, bf16_to_f32(hv.z), a2);
        a3 = fmaf(wc, bf16_to_f32(hv.w), a3);
    }
    // combine the two halves (lanes 0..31 get lane+32's partials)
    a0 += __shfl_xor(a0, 32, 64);
    a1 += __shfl_xor(a1, 32, 64);
    a2 += __shfl_xor(a2, 32, 64);
    a3 += __shfl_xor(a3, 32, 64);
    if (half == 0) {
        float dn = dis[wid];
        float di = deg_inv[wid];
        float4 hs = *reinterpret_cast<const float4*>(&h[(size_t)wid * HF + l32 * 4]);
        float4 o;
        o.x = fmaf(dn, a0, di * hs.x);
        o.y = fmaf(dn, a1, di * hs.y);
        o.z = fmaf(dn, a2, di * hs.z);
        o.w = fmaf(dn, a3, di * hs.w);
        *reinterpret_cast<float4*>(&agg[(size_t)wid * HF + l32 * 4]) = o;
    }
}

// ---------------- residual + layernorm + relu (in-place into h0, + bf16 copy) --------
__global__ void resid_ln_relu(float* __restrict__ h0, unsigned short* __restrict__ h0bf,
                              const float* __restrict__ h1,
                              const float* __restrict__ gamma, const float* __restrict__ beta,
                              int n) {
    int wid = (blockIdx.x * blockDim.x + threadIdx.x) >> 6;
    int lane = threadIdx.x & 63;
    if (wid >= n) return;
    float2 x = *reinterpret_cast<const float2*>(&h1[(size_t)wid * HF + lane * 2]);
    float2 o = *reinterpret_cast<const float2*>(&h0[(size_t)wid * HF + lane * 2]);
    x.x += o.x;
    x.y += o.y;
    float s = x.x + x.y;
#pragma unroll
    for (int m = 1; m < 64; m <<= 1) s += __shfl_xor(s, m, 64);
    float mu = s * (1.0f / HF);
    float dx = x.x - mu, dy = x.y - mu;
    float v = dx * dx + dy * dy;
#pragma unroll
    for (int m = 1; m < 64; m <<= 1) v += __shfl_xor(v, m, 64);
    float r = rsqrtf(v * (1.0f / HF) + 1e-5f);
    float2 g = *reinterpret_cast<const float2*>(&gamma[lane * 2]);
    float2 b = *reinterpret_cast<const float2*>(&beta[lane * 2]);
    float2 t;
    t.x = fmaxf(dx * r * g.x + b.x, 0.f);
    t.y = fmaxf(dy * r * g.y + b.y, 0.f);
    *reinterpret_cast<float2*>(&h0[(size_t)wid * HF + lane * 2]) = t;
    ushort2 tb;
    tb.x = f32_to_bf16_rne(t.x);
    tb.y = f32_to_bf16_rne(t.y);
    *reinterpret_cast<ushort2*>(&h0bf[(size_t)wid * HF + lane * 2]) = tb;
}

extern "C" void kernel_launch(void* const* d_in, const int* in_sizes, int n_in,
                              void* d_out, int out_size, void* d_ws, size_t ws_size,
                              hipStream_t stream) {
    const int N = NN, E = EE;
    const float* in_feat = (const float*)d_in[0];
    const int* row = (const int*)d_in[1];
    const int* col = (const int*)d_in[2];
    const float* lin_w = (const float*)d_in[3];
    const float* lin_b = (const float*)d_in[4];
    const float* conv_w = (const float*)d_in[5];
    const float* conv_b = (const float*)d_in[6];
    const float* root_emb = (const float*)d_in[7];
    const float* ln_gamma = (const float*)d_in[8];
    const float* ln_beta = (const float*)d_in[9];
    float* out = (float*)d_out;

    // workspace layout (4B units)
    float* ws = (float*)d_ws;
    float* deg_inv = ws;                       // N
    float* dis = deg_inv + N;                  // N
    int* cnt = (int*)(dis + N);                // N
    int* row_start = cnt + N;                  // N+1
    int* fill_pos = row_start + N + 1;         // N
    int* bsum = fill_pos + N;                  // 256
    int* csr_col = bsum + 256;                 // E
    float* csr_wc = (float*)(csr_col + E);     // E
    size_t off = (size_t)(csr_wc + E - ws);
    off = (off + 3) & ~(size_t)3;              // 16B align
    float* h0 = ws + off;                          // N*HF f32
    float* agg = h0 + (size_t)N * HF;              // N*HF f32
    unsigned short* hbf = (unsigned short*)(agg + (size_t)N * HF);  // N*HF bf16

    const int NB = (N + 255) / 256;

    hipMemsetAsync(cnt, 0, N * sizeof(int), stream);
    count_deg<<<(E + 255) / 256, 256, 0, stream>>>(row, cnt, E);
    scan_phase1<<<NB, 256, 0, stream>>>(cnt, bsum, N);
    scan_phase2<<<1, 256, 0, stream>>>(bsum, NB);
    scan_phase3<<<NB, 256, 0, stream>>>(cnt, bsum, row_start, fill_pos, deg_inv, dis, N, E);
    fill_csr<<<(E + 255) / 256, 256, 0, stream>>>(row, col, dis, fill_pos, csr_col, csr_wc, E);

    const int GB = (N + 127) / 128;
    const int WB = (N + 3) / 4;

    // h0 = in_feat @ lin_w.T + lin_b  (f32 + bf16 copies)
    gemm_mfma<INF, false><<<GB, 256, 0, stream>>>(in_feat, lin_w, lin_b, h0, hbf,
                                                  nullptr, nullptr, nullptr, N);

    // ---- prop step 0 ----
    aggregate<<<WB, 256, 0, stream>>>(row_start, csr_col, csr_wc, dis, deg_inv, h0, hbf, agg, N);
    gemm_mfma<HF, true><<<GB, 256, 0, stream>>>(agg, conv_w, conv_b, out, nullptr,
                                                h0, deg_inv, root_emb, N);

    // ---- prop step 1 ----
    resid_ln_relu<<<WB, 256, 0, stream>>>(h0, hbf, out, ln_gamma + HF, ln_beta + HF, N);
    aggregate<<<WB, 256, 0, stream>>>(row_start, csr_col, csr_wc, dis, deg_inv, h0, hbf, agg, N);
    gemm_mfma<HF, true><<<GB, 256, 0, stream>>>(agg, conv_w, conv_b, out, nullptr,
                                                h0, deg_inv, root_emb, N);
}

// Round 4
// 326.313 us; speedup vs baseline: 1.6997x; 1.0902x over previous
//
#include <hip/hip_runtime.h>

#define NN 50000
#define EE 600000
#define INF 256
#define HF 128

typedef __attribute__((ext_vector_type(8))) short short8;
typedef __attribute__((ext_vector_type(4))) float floatx4;

// ---------------- bf16 helpers ----------------
__device__ __forceinline__ unsigned short f32_to_bf16_rne(float x) {
    unsigned int u = __float_as_uint(x);
    unsigned int r = (u + 0x7FFFu + ((u >> 16) & 1u)) >> 16;
    return (unsigned short)r;
}
__device__ __forceinline__ float bf16_to_f32(unsigned short h) {
    return __uint_as_float(((unsigned int)h) << 16);
}
__device__ __forceinline__ float bf16lo_u32(unsigned int u) {
    return __uint_as_float(u << 16);
}
__device__ __forceinline__ float bf16hi_u32(unsigned int u) {
    return __uint_as_float(u & 0xFFFF0000u);
}

// ---------------- degree counting ----------------
__global__ void count_deg(const int* __restrict__ row, int* __restrict__ cnt, int E) {
    int e = blockIdx.x * blockDim.x + threadIdx.x;
    if (e < E) atomicAdd(&cnt[row[e]], 1);
}

// ---------------- 3-phase exclusive scan (for CSR row_start) ----------------
__global__ void scan_phase1(const int* __restrict__ cnt, int* __restrict__ bsum, int n) {
    __shared__ int sdata[256];
    int t = threadIdx.x;
    int i = blockIdx.x * 256 + t;
    sdata[t] = (i < n) ? cnt[i] : 0;
    __syncthreads();
    for (int s = 128; s > 0; s >>= 1) {
        if (t < s) sdata[t] += sdata[t + s];
        __syncthreads();
    }
    if (t == 0) bsum[blockIdx.x] = sdata[0];
}

__global__ void scan_phase2(int* __restrict__ bsum, int nb) {
    __shared__ int sdata[256];
    int t = threadIdx.x;
    int v = (t < nb) ? bsum[t] : 0;
    sdata[t] = v;
    __syncthreads();
    for (int s = 1; s < 256; s <<= 1) {
        int add = (t >= s) ? sdata[t - s] : 0;
        __syncthreads();
        sdata[t] += add;
        __syncthreads();
    }
    if (t < nb) bsum[t] = sdata[t] - v;   // exclusive
}

// scan_phase3 + finalize_deg folded
__global__ void scan_phase3(const int* __restrict__ cnt, const int* __restrict__ bsum,
                            int* __restrict__ row_start, int* __restrict__ fill_pos,
                            float* __restrict__ deg_inv, float* __restrict__ dis,
                            int n, int E) {
    __shared__ int sdata[256];
    int t = threadIdx.x;
    int i = blockIdx.x * 256 + t;
    int v = (i < n) ? cnt[i] : 0;
    sdata[t] = v;
    __syncthreads();
    for (int s = 1; s < 256; s <<= 1) {
        int add = (t >= s) ? sdata[t - s] : 0;
        __syncthreads();
        sdata[t] += add;
        __syncthreads();
    }
    if (i < n) {
        int ex = bsum[blockIdx.x] + sdata[t] - v;
        row_start[i] = ex;
        fill_pos[i] = ex;
        float d = (float)(v + 1);
        deg_inv[i] = 1.0f / d;
        dis[i] = rsqrtf(d);
    }
    if (blockIdx.x == 0 && t == 0) row_start[n] = E;
}

__global__ void fill_csr(const int* __restrict__ row, const int* __restrict__ col,
                         const float* __restrict__ dis, int* __restrict__ fill_pos,
                         int* __restrict__ csr_col, float* __restrict__ csr_wc, int E) {
    int e = blockIdx.x * blockDim.x + threadIdx.x;
    if (e < E) {
        int r = row[e];
        int c = col[e];
        int p = atomicAdd(&fill_pos[r], 1);
        csr_col[p] = c;
        csr_wc[p] = dis[c];
    }
}

// ---------------- prepack weights: f32 -> bf16 hi/lo (once per launch) ----------------
// lin_w: 128*256 = 32768 floats (8192 float4); conv_w: 128*128 = 16384 (4096 float4)
__global__ void prepack_w(const float* __restrict__ lw, const float* __restrict__ cw,
                          unsigned short* __restrict__ wlh, unsigned short* __restrict__ wll,
                          unsigned short* __restrict__ wch, unsigned short* __restrict__ wcl) {
    int idx = blockIdx.x * blockDim.x + threadIdx.x;
    const float* src;
    unsigned short *dh, *dl;
    int i;
    if (idx < 8192) {
        src = lw; dh = wlh; dl = wll; i = idx;
    } else if (idx < 12288) {
        src = cw; dh = wch; dl = wcl; i = idx - 8192;
    } else return;
    float4 v = *reinterpret_cast<const float4*>(&src[i * 4]);
    unsigned short hx = f32_to_bf16_rne(v.x), hy = f32_to_bf16_rne(v.y),
                   hz = f32_to_bf16_rne(v.z), hw = f32_to_bf16_rne(v.w);
    ushort4 hp = {hx, hy, hz, hw};
    ushort4 lp = {f32_to_bf16_rne(v.x - bf16_to_f32(hx)), f32_to_bf16_rne(v.y - bf16_to_f32(hy)),
                  f32_to_bf16_rne(v.z - bf16_to_f32(hz)), f32_to_bf16_rne(v.w - bf16_to_f32(hw))};
    *reinterpret_cast<ushort4*>(&dh[i * 4]) = hp;
    *reinterpret_cast<ushort4*>(&dl[i * 4]) = lp;
}

// ---------------- split-bf16 MFMA GEMM: C[M][128] = A[M][K] @ W[128][K]^T ----------------
// TM=64 rows/block (grid 782 -> ~3 blocks/CU), TK=32, 4 waves, wave = 16 rows x 128 cols.
// MODE 0 (lin):  A = f32 (convert on fly). C = acc+bias -> f32 + bf16 copy.
// MODE 1 (conv+LN): A = packed hi/lo. v = acc+conv_b+relu(h+root)*deg_inv; x = v+h;
//                   LN(gamma,beta); relu; h (in-place C) + bf16 copy.
// MODE 2 (conv+out): A packed. C = acc+conv_b+relu(h+root)*deg_inv.
template <int K, int MODE>
__global__ __launch_bounds__(256) void gemm_mfma(
    const float* __restrict__ Af,
    const unsigned short* __restrict__ Ahg, const unsigned short* __restrict__ Alg,
    const unsigned short* __restrict__ Whg, const unsigned short* __restrict__ Wlg,
    const float* __restrict__ bias,
    float* __restrict__ C, unsigned short* __restrict__ Cbf,
    const float* __restrict__ h, const float* __restrict__ deg_inv,
    const float* __restrict__ root,
    const float* __restrict__ gamma, const float* __restrict__ beta,
    int M) {
    constexpr int LDA = 40;  // bf16 row stride: 80 B = 20 banks -> <=2-way conflicts (free)
    __shared__ unsigned short Ah[64 * LDA];
    __shared__ unsigned short Al[64 * LDA];
    __shared__ unsigned short Wh[128 * LDA];
    __shared__ unsigned short Wl[128 * LDA];

    const int t = threadIdx.x;
    const int bm = blockIdx.x * 64;
    const int wave = t >> 6;
    const int lane = t & 63;
    const int lrow = lane & 15;
    const int quad = lane >> 4;
    const int kbase = quad * 8;

    floatx4 acc[8];
#pragma unroll
    for (int nt = 0; nt < 8; ++nt) acc[nt] = (floatx4){0.f, 0.f, 0.f, 0.f};

    for (int k0 = 0; k0 < K; k0 += 32) {
        if (MODE == 0) {
            // A f32 -> hi/lo bf16: 64x32 floats = 512 float4, 2 per thread
#pragma unroll
            for (int r = 0; r < 2; ++r) {
                int f = t + 256 * r;
                int rw = f >> 3;
                int cq = f & 7;
                float4 v = make_float4(0.f, 0.f, 0.f, 0.f);
                int gr = bm + rw;
                if (gr < M) v = *reinterpret_cast<const float4*>(&Af[(size_t)gr * K + k0 + cq * 4]);
                unsigned short hx = f32_to_bf16_rne(v.x), hy = f32_to_bf16_rne(v.y),
                               hz = f32_to_bf16_rne(v.z), hw = f32_to_bf16_rne(v.w);
                unsigned short lx = f32_to_bf16_rne(v.x - bf16_to_f32(hx)),
                               ly = f32_to_bf16_rne(v.y - bf16_to_f32(hy)),
                               lz = f32_to_bf16_rne(v.z - bf16_to_f32(hz)),
                               lw = f32_to_bf16_rne(v.w - bf16_to_f32(hw));
                uint2 hp, lp;
                hp.x = (unsigned)hx | ((unsigned)hy << 16);
                hp.y = (unsigned)hz | ((unsigned)hw << 16);
                lp.x = (unsigned)lx | ((unsigned)ly << 16);
                lp.y = (unsigned)lz | ((unsigned)lw << 16);
                *reinterpret_cast<uint2*>(&Ah[rw * LDA + cq * 4]) = hp;
                *reinterpret_cast<uint2*>(&Al[rw * LDA + cq * 4]) = lp;
            }
        } else {
            // packed A: 64 rows x 4 chunks of 8 ushorts; 1 chunk per thread
            int rw = t >> 2;
            int cq = t & 3;
            int gr = bm + rw;
            uint4 hv = make_uint4(0, 0, 0, 0), lv = make_uint4(0, 0, 0, 0);
            if (gr < M) {
                hv = *reinterpret_cast<const uint4*>(&Ahg[(size_t)gr * K + k0 + cq * 8]);
                lv = *reinterpret_cast<const uint4*>(&Alg[(size_t)gr * K + k0 + cq * 8]);
            }
            *reinterpret_cast<uint2*>(&Ah[rw * LDA + cq * 8]) = make_uint2(hv.x, hv.y);
            *reinterpret_cast<uint2*>(&Ah[rw * LDA + cq * 8 + 4]) = make_uint2(hv.z, hv.w);
            *reinterpret_cast<uint2*>(&Al[rw * LDA + cq * 8]) = make_uint2(lv.x, lv.y);
            *reinterpret_cast<uint2*>(&Al[rw * LDA + cq * 8 + 4]) = make_uint2(lv.z, lv.w);
        }
        // packed W: 128 rows x 4 chunks; 2 chunks per thread
#pragma unroll
        for (int r = 0; r < 2; ++r) {
            int f = t + 256 * r;
            int rw = f >> 2;
            int cq = f & 3;
            uint4 hv = *reinterpret_cast<const uint4*>(&Whg[(size_t)rw * K + k0 + cq * 8]);
            uint4 lv = *reinterpret_cast<const uint4*>(&Wlg[(size_t)rw * K + k0 + cq * 8]);
            *reinterpret_cast<uint2*>(&Wh[rw * LDA + cq * 8]) = make_uint2(hv.x, hv.y);
            *reinterpret_cast<uint2*>(&Wh[rw * LDA + cq * 8 + 4]) = make_uint2(hv.z, hv.w);
            *reinterpret_cast<uint2*>(&Wl[rw * LDA + cq * 8]) = make_uint2(lv.x, lv.y);
            *reinterpret_cast<uint2*>(&Wl[rw * LDA + cq * 8 + 4]) = make_uint2(lv.z, lv.w);
        }
        __syncthreads();

        short8 afh = *reinterpret_cast<const short8*>(&Ah[(wave * 16 + lrow) * LDA + kbase]);
        short8 afl = *reinterpret_cast<const short8*>(&Al[(wave * 16 + lrow) * LDA + kbase]);
        short8 bfh[8], bfl[8];
#pragma unroll
        for (int nt = 0; nt < 8; ++nt) {
            int rw = nt * 16 + lrow;
            bfh[nt] = *reinterpret_cast<const short8*>(&Wh[rw * LDA + kbase]);
            bfl[nt] = *reinterpret_cast<const short8*>(&Wl[rw * LDA + kbase]);
        }
#pragma unroll
        for (int nt = 0; nt < 8; ++nt) {
            acc[nt] = __builtin_amdgcn_mfma_f32_16x16x32_bf16(afh, bfh[nt], acc[nt], 0, 0, 0);
            acc[nt] = __builtin_amdgcn_mfma_f32_16x16x32_bf16(afl, bfh[nt], acc[nt], 0, 0, 0);
            acc[nt] = __builtin_amdgcn_mfma_f32_16x16x32_bf16(afh, bfl[nt], acc[nt], 0, 0, 0);
        }
        __syncthreads();
    }

    // per-column constants (col = nt*16 + lrow, fixed across rows)
    float cb[8], rt[8], gm[8], bt[8];
#pragma unroll
    for (int nt = 0; nt < 8; ++nt) {
        int colh = nt * 16 + lrow;
        cb[nt] = bias[colh];
        if (MODE >= 1) rt[nt] = root[colh];
        if (MODE == 1) { gm[nt] = gamma[colh]; bt[nt] = beta[colh]; }
    }

    // epilogue: C/D layout col=lane&15, row=quad*4+r
#pragma unroll
    for (int r = 0; r < 4; ++r) {
        int grow = bm + wave * 16 + quad * 4 + r;
        if (grow >= M) continue;
        float x[8];
        if (MODE == 0) {
#pragma unroll
            for (int nt = 0; nt < 8; ++nt) x[nt] = acc[nt][r] + cb[nt];
        } else {
            float di = deg_inv[grow];
            float hv[8];
#pragma unroll
            for (int nt = 0; nt < 8; ++nt) hv[nt] = h[(size_t)grow * HF + nt * 16 + lrow];
#pragma unroll
            for (int nt = 0; nt < 8; ++nt) {
                float v = acc[nt][r] + cb[nt] + fmaxf(hv[nt] + rt[nt], 0.f) * di;
                x[nt] = (MODE == 1) ? v + hv[nt] : v;   // MODE1: residual with ori=h
            }
        }
        if (MODE == 1) {
            float s = 0.f;
#pragma unroll
            for (int nt = 0; nt < 8; ++nt) s += x[nt];
#pragma unroll
            for (int m = 1; m < 16; m <<= 1) s += __shfl_xor(s, m, 64);
            float mu = s * (1.0f / HF);
            float var = 0.f;
#pragma unroll
            for (int nt = 0; nt < 8; ++nt) { float d = x[nt] - mu; var += d * d; }
#pragma unroll
            for (int m = 1; m < 16; m <<= 1) var += __shfl_xor(var, m, 64);
            float rs = rsqrtf(var * (1.0f / HF) + 1e-5f);
#pragma unroll
            for (int nt = 0; nt < 8; ++nt) {
                int colh = nt * 16 + lrow;
                float y = fmaxf((x[nt] - mu) * rs * gm[nt] + bt[nt], 0.f);
                C[(size_t)grow * HF + colh] = y;
                Cbf[(size_t)grow * HF + colh] = f32_to_bf16_rne(y);
            }
        } else if (MODE == 0) {
#pragma unroll
            for (int nt = 0; nt < 8; ++nt) {
                int colh = nt * 16 + lrow;
                C[(size_t)grow * HF + colh] = x[nt];
                Cbf[(size_t)grow * HF + colh] = f32_to_bf16_rne(x[nt]);
            }
        } else {
#pragma unroll
            for (int nt = 0; nt < 8; ++nt)
                C[(size_t)grow * HF + nt * 16 + lrow] = x[nt];
        }
    }
}

// ---------------- aggregate: agg = dis[t]*sum_e dis[c]*hbf[c] + deg_inv[t]*h[t] ----------
// one wave per node; quarter-wave per edge (4 gathers in flight); output bf16 hi/lo packed
__global__ void aggregate(const int* __restrict__ row_start, const int* __restrict__ csr_col,
                          const float* __restrict__ csr_wc, const float* __restrict__ dis,
                          const float* __restrict__ deg_inv, const float* __restrict__ h,
                          const unsigned short* __restrict__ hbf,
                          unsigned short* __restrict__ agg_hi, unsigned short* __restrict__ agg_lo,
                          int n) {
    int wid = (blockIdx.x * blockDim.x + threadIdx.x) >> 6;
    int lane = threadIdx.x & 63;
    if (wid >= n) return;
    int q = lane >> 4;
    int l16 = lane & 15;
    int s = row_start[wid];
    int e = row_start[wid + 1];
    float a0 = 0.f, a1 = 0.f, a2 = 0.f, a3 = 0.f, a4 = 0.f, a5 = 0.f, a6 = 0.f, a7 = 0.f;
    for (int j = s + q; j < e; j += 4) {
        int c = csr_col[j];
        float wc = csr_wc[j];
        uint4 hv = *reinterpret_cast<const uint4*>(&hbf[(size_t)c * HF + l16 * 8]);
        a0 = fmaf(wc, bf16lo_u32(hv.x), a0);
        a1 = fmaf(wc, bf16hi_u32(hv.x), a1);
        a2 = fmaf(wc, bf16lo_u32(hv.y), a2);
        a3 = fmaf(wc, bf16hi_u32(hv.y), a3);
        a4 = fmaf(wc, bf16lo_u32(hv.z), a4);
        a5 = fmaf(wc, bf16hi_u32(hv.z), a5);
        a6 = fmaf(wc, bf16lo_u32(hv.w), a6);
        a7 = fmaf(wc, bf16hi_u32(hv.w), a7);
    }
    // reduce the 4 quarters (lanes with equal l16)
#pragma unroll
    for (int m = 16; m < 64; m <<= 1) {
        a0 += __shfl_xor(a0, m, 64);
        a1 += __shfl_xor(a1, m, 64);
        a2 += __shfl_xor(a2, m, 64);
        a3 += __shfl_xor(a3, m, 64);
        a4 += __shfl_xor(a4, m, 64);
        a5 += __shfl_xor(a5, m, 64);
        a6 += __shfl_xor(a6, m, 64);
        a7 += __shfl_xor(a7, m, 64);
    }
    if (q == 0) {
        float dn = dis[wid];
        float di = deg_inv[wid];
        float4 hA = *reinterpret_cast<const float4*>(&h[(size_t)wid * HF + l16 * 8]);
        float4 hB = *reinterpret_cast<const float4*>(&h[(size_t)wid * HF + l16 * 8 + 4]);
        float o[8];
        o[0] = fmaf(dn, a0, di * hA.x);
        o[1] = fmaf(dn, a1, di * hA.y);
        o[2] = fmaf(dn, a2, di * hA.z);
        o[3] = fmaf(dn, a3, di * hA.w);
        o[4] = fmaf(dn, a4, di * hB.x);
        o[5] = fmaf(dn, a5, di * hB.y);
        o[6] = fmaf(dn, a6, di * hB.z);
        o[7] = fmaf(dn, a7, di * hB.w);
        unsigned short hi[8], lo[8];
#pragma unroll
        for (int k = 0; k < 8; ++k) {
            hi[k] = f32_to_bf16_rne(o[k]);
            lo[k] = f32_to_bf16_rne(o[k] - bf16_to_f32(hi[k]));
        }
        uint4 hp, lp;
        hp.x = (unsigned)hi[0] | ((unsigned)hi[1] << 16);
        hp.y = (unsigned)hi[2] | ((unsigned)hi[3] << 16);
        hp.z = (unsigned)hi[4] | ((unsigned)hi[5] << 16);
        hp.w = (unsigned)hi[6] | ((unsigned)hi[7] << 16);
        lp.x = (unsigned)lo[0] | ((unsigned)lo[1] << 16);
        lp.y = (unsigned)lo[2] | ((unsigned)lo[3] << 16);
        lp.z = (unsigned)lo[4] | ((unsigned)lo[5] << 16);
        lp.w = (unsigned)lo[6] | ((unsigned)lo[7] << 16);
        *reinterpret_cast<uint4*>(&agg_hi[(size_t)wid * HF + l16 * 8]) = hp;
        *reinterpret_cast<uint4*>(&agg_lo[(size_t)wid * HF + l16 * 8]) = lp;
    }
}

extern "C" void kernel_launch(void* const* d_in, const int* in_sizes, int n_in,
                              void* d_out, int out_size, void* d_ws, size_t ws_size,
                              hipStream_t stream) {
    const int N = NN, E = EE;
    const float* in_feat = (const float*)d_in[0];
    const int* row = (const int*)d_in[1];
    const int* col = (const int*)d_in[2];
    const float* lin_w = (const float*)d_in[3];
    const float* lin_b = (const float*)d_in[4];
    const float* conv_w = (const float*)d_in[5];
    const float* conv_b = (const float*)d_in[6];
    const float* root_emb = (const float*)d_in[7];
    const float* ln_gamma = (const float*)d_in[8];
    const float* ln_beta = (const float*)d_in[9];
    float* out = (float*)d_out;

    // workspace layout (4B units); all segments kept 16B-aligned
    float* ws = (float*)d_ws;
    float* deg_inv = ws;                         // N
    float* dis = deg_inv + N;                    // N
    int* cnt = (int*)(dis + N);                  // N
    int* row_start = cnt + N;                    // N+4 (padded)
    int* fill_pos = row_start + N + 4;           // N
    int* bsum = fill_pos + N;                    // 256
    int* csr_col = bsum + 256;                   // E
    float* csr_wc = (float*)(csr_col + E);       // E
    unsigned short* wlh = (unsigned short*)(csr_wc + E);  // 32768
    unsigned short* wll = wlh + 32768;                    // 32768
    unsigned short* wch = wll + 32768;                    // 16384
    unsigned short* wcl = wch + 16384;                    // 16384
    float* h0 = (float*)(wcl + 16384);                    // N*HF f32
    unsigned short* hbf = (unsigned short*)(h0 + (size_t)N * HF);   // N*HF bf16
    unsigned short* agg_hi = hbf + (size_t)N * HF;                  // N*HF
    unsigned short* agg_lo = agg_hi + (size_t)N * HF;               // N*HF

    const int NB = (N + 255) / 256;

    hipMemsetAsync(cnt, 0, N * sizeof(int), stream);
    count_deg<<<(E + 255) / 256, 256, 0, stream>>>(row, cnt, E);
    scan_phase1<<<NB, 256, 0, stream>>>(cnt, bsum, N);
    scan_phase2<<<1, 256, 0, stream>>>(bsum, NB);
    scan_phase3<<<NB, 256, 0, stream>>>(cnt, bsum, row_start, fill_pos, deg_inv, dis, N, E);
    fill_csr<<<(E + 255) / 256, 256, 0, stream>>>(row, col, dis, fill_pos, csr_col, csr_wc, E);
    prepack_w<<<48, 256, 0, stream>>>(lin_w, conv_w, wlh, wll, wch, wcl);

    const int GB = (N + 63) / 64;
    const int WB = (N + 3) / 4;

    // h0 = in_feat @ lin_w.T + lin_b  (f32 + bf16 copy)
    gemm_mfma<INF, 0><<<GB, 256, 0, stream>>>(in_feat, nullptr, nullptr, wlh, wll, lin_b,
                                              h0, hbf, nullptr, nullptr, nullptr,
                                              nullptr, nullptr, N);

    // ---- prop step 0 (conv + fused residual/LN/ReLU epilogue -> h0 in-place) ----
    aggregate<<<WB, 256, 0, stream>>>(row_start, csr_col, csr_wc, dis, deg_inv, h0, hbf,
                                      agg_hi, agg_lo, N);
    gemm_mfma<HF, 1><<<GB, 256, 0, stream>>>(nullptr, agg_hi, agg_lo, wch, wcl, conv_b,
                                             h0, hbf, h0, deg_inv, root_emb,
                                             ln_gamma + HF, ln_beta + HF, N);

    // ---- prop step 1 (conv + combine epilogue -> out) ----
    aggregate<<<WB, 256, 0, stream>>>(row_start, csr_col, csr_wc, dis, deg_inv, h0, hbf,
                                      agg_hi, agg_lo, N);
    gemm_mfma<HF, 2><<<GB, 256, 0, stream>>>(nullptr, agg_hi, agg_lo, wch, wcl, conv_b,
                                             out, nullptr, h0, deg_inv, root_emb,
                                             nullptr, nullptr, N);
}